// Round 4
// baseline (99.138 us; speedup 1.0000x reference)
//
#include <hip/hip_runtime.h>

// Problem constants
#define NJ       21
#define CH       3380      // floats per 64-split channel within a batch (26*26*5)
#define BSTRIDE  216320    // floats per batch (64*3380)
#define GROUPS   1690      // 3380 cells / 2 cells-per-thread
#define BLKS_PER_BATCH 7   // ceil(1690/256)
#define NBLK     (256 * BLKS_PER_BATCH)   // 1792

#define CA0 (1920.0f / 26.0f)
#define CA1 (1080.0f / 26.0f)
#define CA2 (1000.0f / 5.0f)
#define INVC0 0.15651764f   // 1/(e^2 - 1)

__device__ __forceinline__ float sigmoidf_(float x) {
    return 1.0f / (1.0f + __expf(-x));
}

__global__ __launch_bounds__(256, 7) void hpo_main(
    const float* __restrict__ pred,
    const float* __restrict__ gt,
    float* __restrict__ partial,
    int*   __restrict__ counter,
    float* __restrict__ out)
{
    __shared__ float s_gs[NJ][3];   // gt * scale
    __shared__ float s_tv[NJ][3];   // target_uvd values at the GT cell
    __shared__ int   s_lin_sh;
    __shared__ float s_w[4];
    __shared__ int   s_last;

    const int bid   = blockIdx.x;
    const int b     = bid / BLKS_PER_BATCH;     // batch
    const int chunk = bid - b * BLKS_PER_BATCH; // cell-chunk within batch
    const int tid   = threadIdx.x;
    const int lane  = tid & 63;
    const int wid   = tid >> 6;

    const float* gtb = gt + b * (NJ * 3);

    if (tid < NJ * 3) {
        const int j = tid / 3;
        const int a = tid - 3 * j;
        const float scale_a = (a == 0) ? 1920.0f : ((a == 1) ? 1080.0f : 1000.0f);
        const float dim_a   = (a == 2) ? 5.0f : 26.0f;
        const int   dimi    = (a == 2) ? 5 : 26;
        const float gv = gtb[tid];
        s_gs[j][a] = gv * scale_a;
        // gidx comes from joint 0 (HAND_ROOT) only
        const float g0v = gtb[a];
        int gi = (int)(g0v * dim_a);
        gi = min(max(gi, 0), dimi - 1);
        s_tv[j][a] = gv * dim_a - (float)gi;
    }
    if (tid == 0) {
        int gi = min(max((int)(gtb[0] * 26.0f), 0), 25);
        int gj = min(max((int)(gtb[1] * 26.0f), 0), 25);
        int gk = min(max((int)(gtb[2] * 5.0f),  0), 4);
        s_lin_sh = 130 * gi + 5 * gj + gk;
    }
    __syncthreads();

    const int s_lin = s_lin_sh;
    const int t = chunk * 256 + tid;
    float acc = 0.0f;

    if (t < GROUPS) {
        const int g0 = 2 * t;
        const float* base = pred + (size_t)b * BSTRIDE + g0;

        // per-cell constants: cell_coord * (scale/dim)
        float cb0[2], cb1[2], cb2[2];
#pragma unroll
        for (int k = 0; k < 2; ++k) {
            const int g   = g0 + k;
            const int w   = g / 130;
            const int rem = g - w * 130;
            const int h   = rem / 5;
            const int d   = rem - h * 5;
            cb0[k] = (float)w * CA0;
            cb1[k] = (float)h * CA1;
            cb2[k] = (float)d * CA2;
        }

        const int klin = s_lin - g0;   // in [0,2) iff this thread owns the GT cell

        float csum[2] = {0.0f, 0.0f};

        // ---- j = 0 (HAND_ROOT: sigmoid applied to inputs) ----
        {
            const float2 x = *(const float2*)(base);
            const float2 y = *(const float2*)(base + CH);
            const float2 z = *(const float2*)(base + 2 * CH);
            const float xv[2] = {sigmoidf_(x.x), sigmoidf_(x.y)};
            const float yv[2] = {sigmoidf_(y.x), sigmoidf_(y.y)};
            const float zv[2] = {sigmoidf_(z.x), sigmoidf_(z.y)};
            const float gs0 = s_gs[0][0], gs1 = s_gs[0][1], gs2 = s_gs[0][2];
#pragma unroll
            for (int k = 0; k < 2; ++k) {
                const float d0 = fmaf(xv[k], CA0, cb0[k] - gs0);
                const float d1 = fmaf(yv[k], CA1, cb1[k] - gs1);
                const float d2 = fmaf(zv[k], CA2, cb2[k] - gs2);
                const float dsq = fmaf(d0, d0, fmaf(d1, d1, fmaf(d2, d2, 1e-5f)));
                const float dist = sqrtf(dsq);
                const float c = (__expf(2.0f - dist * (2.0f / 75.0f)) - 1.0f) * INVC0;
                csum[k] += (dist < 75.0f) ? c : 0.0f;
            }
        }

        // ---- j = 1 .. 20 ----
        for (int j = 1; j < NJ; ++j) {
            const float* p = base + (size_t)(3 * j) * CH;
            const float2 x = *(const float2*)(p);
            const float2 y = *(const float2*)(p + CH);
            const float2 z = *(const float2*)(p + 2 * CH);
            const float xv[2] = {x.x, x.y};
            const float yv[2] = {y.x, y.y};
            const float zv[2] = {z.x, z.y};
            const float gs0 = s_gs[j][0], gs1 = s_gs[j][1], gs2 = s_gs[j][2];
#pragma unroll
            for (int k = 0; k < 2; ++k) {
                const float d0 = fmaf(xv[k], CA0, cb0[k] - gs0);
                const float d1 = fmaf(yv[k], CA1, cb1[k] - gs1);
                const float d2 = fmaf(zv[k], CA2, cb2[k] - gs2);
                const float dsq = fmaf(d0, d0, fmaf(d1, d1, fmaf(d2, d2, 1e-5f)));
                const float dist = sqrtf(dsq);
                const float c = (__expf(2.0f - dist * (2.0f / 75.0f)) - 1.0f) * INVC0;
                csum[k] += (dist < 75.0f) ? c : 0.0f;
            }
        }

        // ---- conf loss (channel 63) ----
        {
            const float2 wc = *(const float2*)(base + (size_t)63 * CH);
            const float wv[2] = {wc.x, wc.y};
#pragma unroll
            for (int k = 0; k < 2; ++k) {
                const float mc = csum[k] * (1.0f / 21.0f);
                const float pconf = sigmoidf_(wv[k]);
                const bool  il = (k == klin);
                const float cm2 = il ? 5.0f : ((mc > 0.6f) ? 0.0f : 0.1f);
                const float tc  = il ? mc : 0.0f;
                const float dd  = pconf - tc;
                acc += 0.5f * cm2 * dd * dd;
            }
        }
    }

    // ---- u/v/d losses: only the GT cell contributes (onehot mask).
    // Exactly one block per batch owns cell s_lin; lanes 0..62 of that block
    // each fetch one (j,a) element in parallel (one round-trip, not 63 serial).
    if ((s_lin >> 1) / 256 == chunk && tid < NJ * 3) {
        const int j = tid / 3;
        const int a = tid - 3 * j;
        float v = pred[(size_t)b * BSTRIDE + (size_t)tid * CH + s_lin];
        if (j == 0) v = sigmoidf_(v);
        const float d = v - s_tv[j][a];
        acc += 0.5f * d * d;
    }

    // ---- wave reduction, then 4-wave combine ----
#pragma unroll
    for (int m = 32; m > 0; m >>= 1) acc += __shfl_xor(acc, m, 64);
    if (lane == 0) s_w[wid] = acc;
    __syncthreads();

    if (tid == 0) {
        const float s = s_w[0] + s_w[1] + s_w[2] + s_w[3];
        partial[bid] = s;
        __threadfence();
        const int old = atomicAdd(counter, 1);
        s_last = (old == NBLK - 1) ? 1 : 0;
    }
    __syncthreads();

    // ---- last block folds the 1792 partials (deterministic index order) ----
    if (s_last && tid < 64) {
        __threadfence();
        float a = 0.0f;
#pragma unroll
        for (int i = 0; i < NBLK / 64; ++i) a += partial[tid + 64 * i];
#pragma unroll
        for (int m = 32; m > 0; m >>= 1) a += __shfl_xor(a, m, 64);
        if (tid == 0) out[0] = a;
    }
}

extern "C" void kernel_launch(void* const* d_in, const int* in_sizes, int n_in,
                              void* d_out, int out_size, void* d_ws, size_t ws_size,
                              hipStream_t stream) {
    const float* pred = (const float*)d_in[0];
    const float* gt   = (const float*)d_in[1];
    float* out        = (float*)d_out;

    int*   counter = (int*)d_ws;                        // 1 int at ws+0
    float* partial = (float*)((char*)d_ws + 256);       // 1792 floats at ws+256

    hipMemsetAsync(d_ws, 0, 256, stream);               // zero the counter
    hpo_main<<<NBLK, 256, 0, stream>>>(pred, gt, partial, counter, out);
}

// Round 5
// 60.541 us; speedup vs baseline: 1.6375x; 1.6375x over previous
//
#include <hip/hip_runtime.h>

// Problem constants
#define NJ       21
#define CH       3380      // floats per 64-split channel within a batch (26*26*5)
#define BSTRIDE  216320    // floats per batch (64*3380)
#define GROUPS   1690      // 3380 cells / 2 cells-per-thread
#define BLKS_PER_BATCH 7   // ceil(1690/256)
#define NBLK     (256 * BLKS_PER_BATCH)   // 1792

#define CA0 (1920.0f / 26.0f)
#define CA1 (1080.0f / 26.0f)
#define CA2 (1000.0f / 5.0f)
#define INVC0 0.15651764f   // 1/(e^2 - 1)

__device__ __forceinline__ float sigmoidf_(float x) {
    return 1.0f / (1.0f + __expf(-x));
}

__global__ __launch_bounds__(256, 7) void hpo_main(
    const float* __restrict__ pred,
    const float* __restrict__ gt,
    float* __restrict__ partial)
{
    __shared__ float s_gs[NJ][3];   // gt * scale
    __shared__ float s_tv[NJ][3];   // target_uvd values at the GT cell
    __shared__ int   s_lin_sh;
    __shared__ float s_w[4];

    const int bid   = blockIdx.x;
    const int b     = bid / BLKS_PER_BATCH;     // batch
    const int chunk = bid - b * BLKS_PER_BATCH; // cell-chunk within batch
    const int tid   = threadIdx.x;
    const int lane  = tid & 63;
    const int wid   = tid >> 6;

    const float* gtb = gt + b * (NJ * 3);

    if (tid < NJ * 3) {
        const int j = tid / 3;
        const int a = tid - 3 * j;
        const float scale_a = (a == 0) ? 1920.0f : ((a == 1) ? 1080.0f : 1000.0f);
        const float dim_a   = (a == 2) ? 5.0f : 26.0f;
        const int   dimi    = (a == 2) ? 5 : 26;
        const float gv = gtb[tid];
        s_gs[j][a] = gv * scale_a;
        // gidx comes from joint 0 (HAND_ROOT) only
        const float g0v = gtb[a];
        int gi = (int)(g0v * dim_a);
        gi = min(max(gi, 0), dimi - 1);
        s_tv[j][a] = gv * dim_a - (float)gi;
    }
    if (tid == 0) {
        int gi = min(max((int)(gtb[0] * 26.0f), 0), 25);
        int gj = min(max((int)(gtb[1] * 26.0f), 0), 25);
        int gk = min(max((int)(gtb[2] * 5.0f),  0), 4);
        s_lin_sh = 130 * gi + 5 * gj + gk;
    }
    __syncthreads();

    const int s_lin = s_lin_sh;
    const int t = chunk * 256 + tid;
    float acc = 0.0f;

    if (t < GROUPS) {
        const int g0 = 2 * t;
        const float* base = pred + (size_t)b * BSTRIDE + g0;

        // per-cell constants: cell_coord * (scale/dim)
        float cb0[2], cb1[2], cb2[2];
#pragma unroll
        for (int k = 0; k < 2; ++k) {
            const int g   = g0 + k;
            const int w   = g / 130;
            const int rem = g - w * 130;
            const int h   = rem / 5;
            const int d   = rem - h * 5;
            cb0[k] = (float)w * CA0;
            cb1[k] = (float)h * CA1;
            cb2[k] = (float)d * CA2;
        }

        const int klin = s_lin - g0;   // in [0,2) iff this thread owns the GT cell

        float csum[2] = {0.0f, 0.0f};

        // ---- joints 0..20, fully unrolled so the compiler can hoist loads
        // (MLP depth limited only by the 72-VGPR budget from launch_bounds) ----
#pragma unroll
        for (int j = 0; j < NJ; ++j) {
            const float* p = base + (size_t)(3 * j) * CH;
            const float2 x = *(const float2*)(p);
            const float2 y = *(const float2*)(p + CH);
            const float2 z = *(const float2*)(p + 2 * CH);
            float xv[2] = {x.x, x.y};
            float yv[2] = {y.x, y.y};
            float zv[2] = {z.x, z.y};
            if (j == 0) {
#pragma unroll
                for (int k = 0; k < 2; ++k) {
                    xv[k] = sigmoidf_(xv[k]);
                    yv[k] = sigmoidf_(yv[k]);
                    zv[k] = sigmoidf_(zv[k]);
                }
            }
            const float gs0 = s_gs[j][0], gs1 = s_gs[j][1], gs2 = s_gs[j][2];
#pragma unroll
            for (int k = 0; k < 2; ++k) {
                const float d0 = fmaf(xv[k], CA0, cb0[k] - gs0);
                const float d1 = fmaf(yv[k], CA1, cb1[k] - gs1);
                const float d2 = fmaf(zv[k], CA2, cb2[k] - gs2);
                const float dsq = fmaf(d0, d0, fmaf(d1, d1, fmaf(d2, d2, 1e-5f)));
                const float dist = dsq * __frsqrt_rn(dsq);   // dsq >= 1e-5
                const float c = (__expf(2.0f - dist * (2.0f / 75.0f)) - 1.0f) * INVC0;
                csum[k] += (dist < 75.0f) ? c : 0.0f;
            }
        }

        // ---- conf loss (channel 63) ----
        {
            const float2 wc = *(const float2*)(base + (size_t)63 * CH);
            const float wv[2] = {wc.x, wc.y};
#pragma unroll
            for (int k = 0; k < 2; ++k) {
                const float mc = csum[k] * (1.0f / 21.0f);
                const float pconf = sigmoidf_(wv[k]);
                const bool  il = (k == klin);
                const float cm2 = il ? 5.0f : ((mc > 0.6f) ? 0.0f : 0.1f);
                const float tc  = il ? mc : 0.0f;
                const float dd  = pconf - tc;
                acc += 0.5f * cm2 * dd * dd;
            }
        }
    }

    // ---- u/v/d losses: only the GT cell contributes (onehot mask).
    // Exactly one block per batch owns cell s_lin; lanes 0..62 of that block
    // each fetch one (j,a) element in parallel (verified correct in R4).
    if ((s_lin >> 1) / 256 == chunk && tid < NJ * 3) {
        const int j = tid / 3;
        const int a = tid - 3 * j;
        float v = pred[(size_t)b * BSTRIDE + (size_t)tid * CH + s_lin];
        if (j == 0) v = sigmoidf_(v);
        const float d = v - s_tv[j][a];
        acc += 0.5f * d * d;
    }

    // ---- wave reduction, then 4-wave combine ----
#pragma unroll
    for (int m = 32; m > 0; m >>= 1) acc += __shfl_xor(acc, m, 64);
    if (lane == 0) s_w[wid] = acc;
    __syncthreads();

    if (tid == 0) partial[bid] = s_w[0] + s_w[1] + s_w[2] + s_w[3];
}

__global__ __launch_bounds__(256) void hpo_reduce(
    const float* __restrict__ partial,
    float* __restrict__ out)
{
    __shared__ float s[256];
    const int tid = threadIdx.x;
    float a = 0.0f;
#pragma unroll
    for (int i = 0; i < BLKS_PER_BATCH; ++i)   // 1792 = 7 * 256
        a += partial[tid + 256 * i];
    s[tid] = a;
    __syncthreads();
    for (int st = 128; st > 0; st >>= 1) {
        if (tid < st) s[tid] += s[tid + st];
        __syncthreads();
    }
    if (tid == 0) out[0] = s[0];
}

extern "C" void kernel_launch(void* const* d_in, const int* in_sizes, int n_in,
                              void* d_out, int out_size, void* d_ws, size_t ws_size,
                              hipStream_t stream) {
    const float* pred = (const float*)d_in[0];
    const float* gt   = (const float*)d_in[1];
    float* out        = (float*)d_out;
    float* partial    = (float*)d_ws;   // 1792 floats

    hpo_main<<<NBLK, 256, 0, stream>>>(pred, gt, partial);
    hpo_reduce<<<1, 256, 0, stream>>>(partial, out);
}

// Round 6
// 42.418 us; speedup vs baseline: 2.3372x; 1.4273x over previous
//
#include <hip/hip_runtime.h>

// Problem constants
#define NJ       21
#define CH       3380      // floats per 64-split channel within a batch (26*26*5)
#define BSTRIDE  216320    // floats per batch (64*3380)
#define GROUPS   1690      // 3380 cells / 2 cells-per-thread
#define BLKS_PER_BATCH 7   // ceil(1690/256)
#define NBLK     (256 * BLKS_PER_BATCH)   // 1792

#define CA0 (1920.0f / 26.0f)
#define CA1 (1080.0f / 26.0f)
#define CA2 (1000.0f / 5.0f)
#define INVC0 0.15651764f   // 1/(e^2 - 1)

__device__ __forceinline__ float sigmoidf_(float x) {
    return 1.0f / (1.0f + __expf(-x));
}

__global__ __launch_bounds__(256, 7) void hpo_main(
    const float* __restrict__ pred,
    const float* __restrict__ gt,
    float* __restrict__ partial)
{
    __shared__ float s_gs[NJ][3];   // gt * scale
    __shared__ float s_tv[NJ][3];   // target_uvd values at the GT cell
    __shared__ int   s_lin_sh;
    __shared__ float s_w[4];

    const int bid   = blockIdx.x;
    const int b     = bid / BLKS_PER_BATCH;     // batch
    const int chunk = bid - b * BLKS_PER_BATCH; // cell-chunk within batch
    const int tid   = threadIdx.x;
    const int lane  = tid & 63;
    const int wid   = tid >> 6;

    const float* gtb = gt + b * (NJ * 3);

    if (tid < NJ * 3) {
        const int j = tid / 3;
        const int a = tid - 3 * j;
        const float scale_a = (a == 0) ? 1920.0f : ((a == 1) ? 1080.0f : 1000.0f);
        const float dim_a   = (a == 2) ? 5.0f : 26.0f;
        const int   dimi    = (a == 2) ? 5 : 26;
        const float gv = gtb[tid];
        s_gs[j][a] = gv * scale_a;
        // gidx comes from joint 0 (HAND_ROOT) only
        const float g0v = gtb[a];
        int gi = (int)(g0v * dim_a);
        gi = min(max(gi, 0), dimi - 1);
        s_tv[j][a] = gv * dim_a - (float)gi;
    }
    if (tid == 0) {
        int gi = min(max((int)(gtb[0] * 26.0f), 0), 25);
        int gj = min(max((int)(gtb[1] * 26.0f), 0), 25);
        int gk = min(max((int)(gtb[2] * 5.0f),  0), 4);
        s_lin_sh = 130 * gi + 5 * gj + gk;
    }
    __syncthreads();

    const int s_lin = s_lin_sh;
    const int t = chunk * 256 + tid;
    float acc = 0.0f;

    if (t < GROUPS) {
        const int g0 = 2 * t;
        const float* base = pred + (size_t)b * BSTRIDE + g0;

        // per-cell constants: cell_coord * (scale/dim)
        float cb0[2], cb1[2], cb2[2];
#pragma unroll
        for (int k = 0; k < 2; ++k) {
            const int g   = g0 + k;
            const int w   = g / 130;
            const int rem = g - w * 130;
            const int h   = rem / 5;
            const int d   = rem - h * 5;
            cb0[k] = (float)w * CA0;
            cb1[k] = (float)h * CA1;
            cb2[k] = (float)d * CA2;
        }

        const int klin = s_lin - g0;   // in [0,2) iff this thread owns the GT cell

        float csum[2] = {0.0f, 0.0f};

        // ---- j = 0 (HAND_ROOT: sigmoid applied to inputs) ----
        {
            const float2 x = *(const float2*)(base);
            const float2 y = *(const float2*)(base + CH);
            const float2 z = *(const float2*)(base + 2 * CH);
            const float xv[2] = {sigmoidf_(x.x), sigmoidf_(x.y)};
            const float yv[2] = {sigmoidf_(y.x), sigmoidf_(y.y)};
            const float zv[2] = {sigmoidf_(z.x), sigmoidf_(z.y)};
            const float gs0 = s_gs[0][0], gs1 = s_gs[0][1], gs2 = s_gs[0][2];
#pragma unroll
            for (int k = 0; k < 2; ++k) {
                const float d0 = fmaf(xv[k], CA0, cb0[k] - gs0);
                const float d1 = fmaf(yv[k], CA1, cb1[k] - gs1);
                const float d2 = fmaf(zv[k], CA2, cb2[k] - gs2);
                const float dsq = fmaf(d0, d0, fmaf(d1, d1, fmaf(d2, d2, 1e-5f)));
                const float dist = sqrtf(dsq);
                const float c = (__expf(2.0f - dist * (2.0f / 75.0f)) - 1.0f) * INVC0;
                csum[k] += (dist < 75.0f) ? c : 0.0f;
            }
        }

        // ---- j = 1 .. 20, groups of 4: 12 float2 loads hoisted per group ----
#pragma unroll 4
        for (int j = 1; j < NJ; ++j) {
            const float* p = base + (size_t)(3 * j) * CH;
            const float2 x = *(const float2*)(p);
            const float2 y = *(const float2*)(p + CH);
            const float2 z = *(const float2*)(p + 2 * CH);
            const float xv[2] = {x.x, x.y};
            const float yv[2] = {y.x, y.y};
            const float zv[2] = {z.x, z.y};
            const float gs0 = s_gs[j][0], gs1 = s_gs[j][1], gs2 = s_gs[j][2];
#pragma unroll
            for (int k = 0; k < 2; ++k) {
                const float d0 = fmaf(xv[k], CA0, cb0[k] - gs0);
                const float d1 = fmaf(yv[k], CA1, cb1[k] - gs1);
                const float d2 = fmaf(zv[k], CA2, cb2[k] - gs2);
                const float dsq = fmaf(d0, d0, fmaf(d1, d1, fmaf(d2, d2, 1e-5f)));
                const float dist = sqrtf(dsq);
                const float c = (__expf(2.0f - dist * (2.0f / 75.0f)) - 1.0f) * INVC0;
                csum[k] += (dist < 75.0f) ? c : 0.0f;
            }
        }

        // ---- conf loss (channel 63) ----
        {
            const float2 wc = *(const float2*)(base + (size_t)63 * CH);
            const float wv[2] = {wc.x, wc.y};
#pragma unroll
            for (int k = 0; k < 2; ++k) {
                const float mc = csum[k] * (1.0f / 21.0f);
                const float pconf = sigmoidf_(wv[k]);
                const bool  il = (k == klin);
                const float cm2 = il ? 5.0f : ((mc > 0.6f) ? 0.0f : 0.1f);
                const float tc  = il ? mc : 0.0f;
                const float dd  = pconf - tc;
                acc += 0.5f * cm2 * dd * dd;
            }
        }
    }

    // ---- u/v/d losses: only the GT cell contributes (onehot mask).
    // Exactly one block per batch owns cell s_lin; lanes 0..62 of that block
    // each fetch one (j,a) element in parallel (verified correct in R4/R5).
    if ((s_lin >> 1) / 256 == chunk && tid < NJ * 3) {
        const int j = tid / 3;
        const int a = tid - 3 * j;
        float v = pred[(size_t)b * BSTRIDE + (size_t)tid * CH + s_lin];
        if (j == 0) v = sigmoidf_(v);
        const float d = v - s_tv[j][a];
        acc += 0.5f * d * d;
    }

    // ---- wave reduction, then 4-wave combine ----
#pragma unroll
    for (int m = 32; m > 0; m >>= 1) acc += __shfl_xor(acc, m, 64);
    if (lane == 0) s_w[wid] = acc;
    __syncthreads();

    if (tid == 0) partial[bid] = s_w[0] + s_w[1] + s_w[2] + s_w[3];
}

__global__ __launch_bounds__(256) void hpo_reduce(
    const float* __restrict__ partial,
    float* __restrict__ out)
{
    __shared__ float s[256];
    const int tid = threadIdx.x;
    float a = 0.0f;
#pragma unroll
    for (int i = 0; i < BLKS_PER_BATCH; ++i)   // 1792 = 7 * 256
        a += partial[tid + 256 * i];
    s[tid] = a;
    __syncthreads();
    for (int st = 128; st > 0; st >>= 1) {
        if (tid < st) s[tid] += s[tid + st];
        __syncthreads();
    }
    if (tid == 0) out[0] = s[0];
}

extern "C" void kernel_launch(void* const* d_in, const int* in_sizes, int n_in,
                              void* d_out, int out_size, void* d_ws, size_t ws_size,
                              hipStream_t stream) {
    const float* pred = (const float*)d_in[0];
    const float* gt   = (const float*)d_in[1];
    float* out        = (float*)d_out;
    float* partial    = (float*)d_ws;   // 1792 floats

    hpo_main<<<NBLK, 256, 0, stream>>>(pred, gt, partial);
    hpo_reduce<<<1, 256, 0, stream>>>(partial, out);
}

// Round 7
// 27.760 us; speedup vs baseline: 3.5713x; 1.5280x over previous
//
#include <hip/hip_runtime.h>

// Problem constants
#define NJ       21
#define CH       3380      // floats per 64-split channel within a batch (26*26*5)
#define BSTRIDE  216320    // floats per batch (64*3380)
#define GROUPS   1690      // 3380 cells / 2 cells-per-thread
#define BLKS_PER_BATCH 7   // ceil(1690/256)
#define NBLK     (256 * BLKS_PER_BATCH)   // 1792

#define CA0 (1920.0f / 26.0f)
#define CA1 (1080.0f / 26.0f)
#define CA2 (1000.0f / 5.0f)
#define INVC0 0.15651764f   // 1/(e^2 - 1)
#define SKIP_TH 76.0f       // |d0| >= 76 => dist > 75 guaranteed (incl. fp rounding)

__device__ __forceinline__ float sigmoidf_(float x) {
    return 1.0f / (1.0f + __expf(-x));
}

// Full per-joint term for both cells of this thread; only called when the
// wave-vote says some lane might be inside the 75px ball (x-test passed).
__device__ __forceinline__ void joint_term(
    const float* __restrict__ p, bool sig,
    const float d0_[2], float gs1, float gs2,
    const float cb1_[2], const float cb2_[2], float csum[2])
{
    const float2 y = *(const float2*)(p + CH);
    const float2 z = *(const float2*)(p + 2 * CH);
    float yv[2] = {y.x, y.y};
    float zv[2] = {z.x, z.y};
    if (sig) {
        yv[0] = sigmoidf_(yv[0]); yv[1] = sigmoidf_(yv[1]);
        zv[0] = sigmoidf_(zv[0]); zv[1] = sigmoidf_(zv[1]);
    }
#pragma unroll
    for (int k = 0; k < 2; ++k) {
        const float d1 = fmaf(yv[k], CA1, cb1_[k] - gs1);
        const float d2 = fmaf(zv[k], CA2, cb2_[k] - gs2);
        const float dsq = fmaf(d0_[k], d0_[k], fmaf(d1, d1, fmaf(d2, d2, 1e-5f)));
        const float dist = sqrtf(dsq);
        const float c = (__expf(2.0f - dist * (2.0f / 75.0f)) - 1.0f) * INVC0;
        csum[k] += (dist < 75.0f) ? c : 0.0f;
    }
}

__global__ __launch_bounds__(256, 7) void hpo_main(
    const float* __restrict__ pred,
    const float* __restrict__ gt,
    float* __restrict__ partial)
{
    __shared__ float s_gs[NJ][3];   // gt * scale
    __shared__ float s_tv[NJ][3];   // target_uvd values at the GT cell
    __shared__ int   s_lin_sh;
    __shared__ float s_w[4];

    const int bid   = blockIdx.x;
    const int b     = bid / BLKS_PER_BATCH;     // batch
    const int chunk = bid - b * BLKS_PER_BATCH; // cell-chunk within batch
    const int tid   = threadIdx.x;
    const int lane  = tid & 63;
    const int wid   = tid >> 6;

    const float* gtb = gt + b * (NJ * 3);

    if (tid < NJ * 3) {
        const int j = tid / 3;
        const int a = tid - 3 * j;
        const float scale_a = (a == 0) ? 1920.0f : ((a == 1) ? 1080.0f : 1000.0f);
        const float dim_a   = (a == 2) ? 5.0f : 26.0f;
        const int   dimi    = (a == 2) ? 5 : 26;
        const float gv = gtb[tid];
        s_gs[j][a] = gv * scale_a;
        // gidx comes from joint 0 (HAND_ROOT) only
        const float g0v = gtb[a];
        int gi = (int)(g0v * dim_a);
        gi = min(max(gi, 0), dimi - 1);
        s_tv[j][a] = gv * dim_a - (float)gi;
    }
    if (tid == 0) {
        int gi = min(max((int)(gtb[0] * 26.0f), 0), 25);
        int gj = min(max((int)(gtb[1] * 26.0f), 0), 25);
        int gk = min(max((int)(gtb[2] * 5.0f),  0), 4);
        s_lin_sh = 130 * gi + 5 * gj + gk;
    }
    __syncthreads();

    const int s_lin = s_lin_sh;
    const int t = chunk * 256 + tid;
    float acc = 0.0f;

    if (t < GROUPS) {
        const int g0 = 2 * t;
        const float* base = pred + (size_t)b * BSTRIDE + g0;

        // per-cell constants: cell_coord * (scale/dim)
        float cb0[2], cb1[2], cb2[2];
#pragma unroll
        for (int k = 0; k < 2; ++k) {
            const int g   = g0 + k;
            const int w   = g / 130;
            const int rem = g - w * 130;
            const int h   = rem / 5;
            const int d   = rem - h * 5;
            cb0[k] = (float)w * CA0;
            cb1[k] = (float)h * CA1;
            cb2[k] = (float)d * CA2;
        }

        const int klin = s_lin - g0;   // in [0,2) iff this thread owns the GT cell

        float csum[2] = {0.0f, 0.0f};

        // ---- j = 0 (HAND_ROOT: sigmoid on inputs), x-test then conditional y/z ----
        {
            const float2 x = *(const float2*)(base);
            const float xs0 = sigmoidf_(x.x), xs1 = sigmoidf_(x.y);
            const float gs0 = s_gs[0][0];
            const float d0_[2] = { fmaf(xs0, CA0, cb0[0] - gs0),
                                   fmaf(xs1, CA0, cb0[1] - gs0) };
            if (__any(fabsf(d0_[0]) < SKIP_TH || fabsf(d0_[1]) < SKIP_TH))
                joint_term(base, true, d0_, s_gs[0][1], s_gs[0][2], cb1, cb2, csum);
        }

        // ---- j = 1..20 in 5 groups of 4: batch the 4 x-loads, wave-vote each ----
        for (int jb = 1; jb <= 17; jb += 4) {
            const float* p0 = base + (size_t)(3 * jb) * CH;
            const float* p1 = p0 + 3 * (size_t)CH;
            const float* p2 = p0 + 6 * (size_t)CH;
            const float* p3 = p0 + 9 * (size_t)CH;
            const float2 x0 = *(const float2*)p0;
            const float2 x1 = *(const float2*)p1;
            const float2 x2 = *(const float2*)p2;
            const float2 x3 = *(const float2*)p3;

            const float d00[2] = { fmaf(x0.x, CA0, cb0[0] - s_gs[jb+0][0]),
                                   fmaf(x0.y, CA0, cb0[1] - s_gs[jb+0][0]) };
            const float d01[2] = { fmaf(x1.x, CA0, cb0[0] - s_gs[jb+1][0]),
                                   fmaf(x1.y, CA0, cb0[1] - s_gs[jb+1][0]) };
            const float d02[2] = { fmaf(x2.x, CA0, cb0[0] - s_gs[jb+2][0]),
                                   fmaf(x2.y, CA0, cb0[1] - s_gs[jb+2][0]) };
            const float d03[2] = { fmaf(x3.x, CA0, cb0[0] - s_gs[jb+3][0]),
                                   fmaf(x3.y, CA0, cb0[1] - s_gs[jb+3][0]) };

            if (__any(fabsf(d00[0]) < SKIP_TH || fabsf(d00[1]) < SKIP_TH))
                joint_term(p0, false, d00, s_gs[jb+0][1], s_gs[jb+0][2], cb1, cb2, csum);
            if (__any(fabsf(d01[0]) < SKIP_TH || fabsf(d01[1]) < SKIP_TH))
                joint_term(p1, false, d01, s_gs[jb+1][1], s_gs[jb+1][2], cb1, cb2, csum);
            if (__any(fabsf(d02[0]) < SKIP_TH || fabsf(d02[1]) < SKIP_TH))
                joint_term(p2, false, d02, s_gs[jb+2][1], s_gs[jb+2][2], cb1, cb2, csum);
            if (__any(fabsf(d03[0]) < SKIP_TH || fabsf(d03[1]) < SKIP_TH))
                joint_term(p3, false, d03, s_gs[jb+3][1], s_gs[jb+3][2], cb1, cb2, csum);
        }

        // ---- conf loss (channel 63) ----
        {
            const float2 wc = *(const float2*)(base + (size_t)63 * CH);
            const float wv[2] = {wc.x, wc.y};
#pragma unroll
            for (int k = 0; k < 2; ++k) {
                const float mc = csum[k] * (1.0f / 21.0f);
                const float pconf = sigmoidf_(wv[k]);
                const bool  il = (k == klin);
                const float cm2 = il ? 5.0f : ((mc > 0.6f) ? 0.0f : 0.1f);
                const float tc  = il ? mc : 0.0f;
                const float dd  = pconf - tc;
                acc += 0.5f * cm2 * dd * dd;
            }
        }
    }

    // ---- u/v/d losses: only the GT cell contributes (onehot mask).
    // Exactly one block per batch owns cell s_lin; lanes 0..62 of that block
    // each fetch one (j,a) element in parallel (verified correct R4-R6).
    if ((s_lin >> 1) / 256 == chunk && tid < NJ * 3) {
        const int j = tid / 3;
        const int a = tid - 3 * j;
        float v = pred[(size_t)b * BSTRIDE + (size_t)tid * CH + s_lin];
        if (j == 0) v = sigmoidf_(v);
        const float d = v - s_tv[j][a];
        acc += 0.5f * d * d;
    }

    // ---- wave reduction, then 4-wave combine ----
#pragma unroll
    for (int m = 32; m > 0; m >>= 1) acc += __shfl_xor(acc, m, 64);
    if (lane == 0) s_w[wid] = acc;
    __syncthreads();

    if (tid == 0) partial[bid] = s_w[0] + s_w[1] + s_w[2] + s_w[3];
}

__global__ __launch_bounds__(256) void hpo_reduce(
    const float* __restrict__ partial,
    float* __restrict__ out)
{
    __shared__ float s[256];
    const int tid = threadIdx.x;
    float a = 0.0f;
#pragma unroll
    for (int i = 0; i < BLKS_PER_BATCH; ++i)   // 1792 = 7 * 256
        a += partial[tid + 256 * i];
    s[tid] = a;
    __syncthreads();
    for (int st = 128; st > 0; st >>= 1) {
        if (tid < st) s[tid] += s[tid + st];
        __syncthreads();
    }
    if (tid == 0) out[0] = s[0];
}

extern "C" void kernel_launch(void* const* d_in, const int* in_sizes, int n_in,
                              void* d_out, int out_size, void* d_ws, size_t ws_size,
                              hipStream_t stream) {
    const float* pred = (const float*)d_in[0];
    const float* gt   = (const float*)d_in[1];
    float* out        = (float*)d_out;
    float* partial    = (float*)d_ws;   // 1792 floats

    hpo_main<<<NBLK, 256, 0, stream>>>(pred, gt, partial);
    hpo_reduce<<<1, 256, 0, stream>>>(partial, out);
}